// Round 7
// baseline (29.482 us; speedup 1.0000x reference)
//
#include <hip/hip_runtime.h>

// Problem constants
#define NBATCH 8
#define HH 512
#define WW 512
#define NPIX (HH * WW)                 // 262144
#define IMG_ELEMS (NBATCH * 3 * NPIX)  // 6291456 floats per stitched output
#define OFF_ALBEDO 0
#define OFF_NORMAL ((size_t)IMG_ELEMS)
#define OFF_SHADING ((size_t)(2 * IMG_ELEMS))
#define OFF_LIGHT ((size_t)(3 * IMG_ELEMS))
#define N_LIGHT (NBATCH * 27 * 49)     // 10584
#define OFF_LOSS (OFF_LIGHT + N_LIGHT)
#define NBLK (NBATCH * 8 * 8)          // 512 blocks: one full 64x64 tile each
// Tile-sum table: P[bid][c], c padded to 8 -> 512*8 floats = 16 KB in d_ws.
// Every slot written every call by exactly one block -> no zeroing, no atomics.

typedef float f32x4 __attribute__((ext_vector_type(4)));

__device__ __forceinline__ float fast_tanh(float x) {
    // tanh(x) = 1 - 2/(exp(2x)+1); saturates correctly at +/-inf of exp
    float e = __expf(2.0f * x);
    return 1.0f - 2.0f / (e + 1.0f);
}

// One block = 256 threads = one 64x64 tile; 16 px/thread as FOUR dense 4-px
// row-chunks (rows y, y+16, y+32, y+48). Every load/store instruction is
// 64 lanes x 16B contiguous = 1 KB dense.
// grid = N * 8(ti) * 8(tj) = 512 blocks = 2048 waves, 8 waves/CU.
__global__ __launch_bounds__(256) void fused_heads_kernel(
    const float* __restrict__ inT, const float* __restrict__ inN,
    const float* __restrict__ Wa, const float* __restrict__ ba,
    const float* __restrict__ Wn, const float* __restrict__ bn,
    const float* __restrict__ Ws, const float* __restrict__ bs,
    float* __restrict__ out, float* __restrict__ P) {
    int bid = blockIdx.x;
    int n = bid >> 6;           // / 64
    int rem = bid & 63;
    int ti = rem >> 3;
    int tj = rem & 7;

    int t = threadIdx.x;
    int rowc = t >> 4;          // 0..15
    int col4 = t & 15;          // 0..15
    int y = ti * 64 + rowc;     // chunks at y + 16k
    int x = tj * 64 + col4 * 4;

    // 24 independent fully-dense f32x4 loads (6 channels x 4 row-chunks)
    f32x4 f[4][6];
    size_t base[4];
    base[0] = ((size_t)(n * 3) * HH + y) * WW + x;
#pragma unroll
    for (int k = 1; k < 4; ++k) base[k] = base[0] + (size_t)(16 * k) * WW;
#pragma unroll
    for (int k = 0; k < 4; ++k) {
#pragma unroll
        for (int c = 0; c < 3; ++c) {
            f[k][c]     = *reinterpret_cast<const f32x4*>(inT + base[k] + (size_t)c * NPIX);
            f[k][c + 3] = *reinterpret_cast<const f32x4*>(inN + base[k] + (size_t)c * NPIX);
        }
    }

    // Three heads: out[n,o,y,x] = tanh(W[o,:].feat + b[o])
    // (stitch weights are separable and sum to 1 at every pixel -> stitch == identity;
    //  overlap_loss is identically zero since overlapping patches see the same pixels)
#pragma unroll
    for (int h = 0; h < 3; ++h) {
        const float* W = (h == 0) ? Wa : (h == 1) ? Wn : Ws;
        const float* b = (h == 0) ? ba : (h == 1) ? bn : bs;
        float* o_ptr = out + ((h == 0) ? OFF_ALBEDO : (h == 1) ? OFF_NORMAL : OFF_SHADING);
#pragma unroll
        for (int o = 0; o < 3; ++o) {
            float bv = b[o];
#pragma unroll
            for (int k = 0; k < 4; ++k) {
                f32x4 A = {bv, bv, bv, bv};
#pragma unroll
                for (int c = 0; c < 6; ++c) {
                    float w = W[o * 6 + c];
                    A.x = fmaf(w, f[k][c].x, A.x);
                    A.y = fmaf(w, f[k][c].y, A.y);
                    A.z = fmaf(w, f[k][c].z, A.z);
                    A.w = fmaf(w, f[k][c].w, A.w);
                }
                f32x4 r = {fast_tanh(A.x), fast_tanh(A.y), fast_tanh(A.z), fast_tanh(A.w)};
                *reinterpret_cast<f32x4*>(o_ptr + base[k] + (size_t)o * NPIX) = r;
            }
        }
    }

    // Per-channel sums of this thread's 16 px -> block-local full 64x64 tile sum
    float s[6];
#pragma unroll
    for (int c = 0; c < 6; ++c) {
        s[c] = 0.f;
#pragma unroll
        for (int k = 0; k < 4; ++k)
            s[c] += f[k][c].x + f[k][c].y + f[k][c].z + f[k][c].w;
    }

    // wave (64-lane) butterfly reduce
#pragma unroll
    for (int off = 32; off > 0; off >>= 1) {
#pragma unroll
        for (int c = 0; c < 6; ++c) s[c] += __shfl_down(s[c], off, 64);
    }

    __shared__ float red[4][6];
    int wave = t >> 6;
    int lane = t & 63;
    if (lane == 0) {
#pragma unroll
        for (int c = 0; c < 6; ++c) red[wave][c] = s[c];
    }
    __syncthreads();
    if (t < 6) {
        float v = red[0][t] + red[1][t] + red[2][t] + red[3][t];
        P[(size_t)bid * 8 + t] = v;   // full tile sum; deterministic slot, no atomics
    }
}

// lighting: pooled mean over each 128x128 patch = sum of 4 tile sums (2x2) / 16384
__global__ __launch_bounds__(256) void lighting_kernel(
    const float* __restrict__ P, const float* __restrict__ Wl,
    const float* __restrict__ bl, float* __restrict__ out) {
    int tid = blockIdx.x * blockDim.x + threadIdx.x;
    if (tid > N_LIGHT) return;
    if (tid == N_LIGHT) {
        out[OFF_LOSS] = 0.0f;  // overlap_loss is identically zero
        return;
    }
    int n = tid / (27 * 49);
    int r = tid % (27 * 49);
    int o = r / 49;
    int r2 = r % 49;
    int i = r2 / 7;
    int j = r2 % 7;

    f32x4 s0 = {0.f, 0.f, 0.f, 0.f};   // channels 0..3
    float s4 = 0.f, s5 = 0.f;          // channels 4..5
#pragma unroll
    for (int di = 0; di < 2; ++di) {
#pragma unroll
        for (int dj = 0; dj < 2; ++dj) {
            int b = (n * 8 + (i + di)) * 8 + (j + dj);
            const float* p = P + (size_t)b * 8;
            f32x4 v0 = *reinterpret_cast<const f32x4*>(p);
            f32x4 v1 = *reinterpret_cast<const f32x4*>(p + 4);
            s0 += v0;
            s4 += v1.x;
            s5 += v1.y;
        }
    }
    float acc = bl[o];
    const float inv = 1.0f / 16384.0f;
    acc = fmaf(Wl[o * 6 + 0], s0.x * inv, acc);
    acc = fmaf(Wl[o * 6 + 1], s0.y * inv, acc);
    acc = fmaf(Wl[o * 6 + 2], s0.z * inv, acc);
    acc = fmaf(Wl[o * 6 + 3], s0.w * inv, acc);
    acc = fmaf(Wl[o * 6 + 4], s4 * inv, acc);
    acc = fmaf(Wl[o * 6 + 5], s5 * inv, acc);
    out[OFF_LIGHT + tid] = acc;
}

extern "C" void kernel_launch(void* const* d_in, const int* in_sizes, int n_in,
                              void* d_out, int out_size, void* d_ws, size_t ws_size,
                              hipStream_t stream) {
    const float* inT = (const float*)d_in[0];
    const float* inN = (const float*)d_in[1];
    const float* Wa = (const float*)d_in[2];
    const float* ba = (const float*)d_in[3];
    const float* Wn = (const float*)d_in[4];
    const float* bn = (const float*)d_in[5];
    const float* Ws = (const float*)d_in[6];
    const float* bs = (const float*)d_in[7];
    const float* Wl = (const float*)d_in[8];
    const float* bl = (const float*)d_in[9];
    float* out = (float*)d_out;
    float* P = (float*)d_ws;

    fused_heads_kernel<<<NBLK, 256, 0, stream>>>(
        inT, inN, Wa, ba, Wn, bn, Ws, bs, out, P);

    lighting_kernel<<<(N_LIGHT + 1 + 255) / 256, 256, 0, stream>>>(P, Wl, bl, out);
}